// Round 13
// baseline (1292.776 us; speedup 1.0000x reference)
//
#include <hip/hip_runtime.h>

#define B_ 16
#define CN_ 22
#define T_ 1000
#define EXP_ 300
#define FCH_ 150
#define SPD_ 100
#define NSWEEP 8

typedef float v2f __attribute__((ext_vector_type(2)));

// workspace layout (bytes)
static constexpr unsigned long long OFF_M2   = 0ull;
static constexpr unsigned long long OFF_HCAT = 65536ull;
static constexpr unsigned long long OFF_XC   = OFF_HCAT + 28800000ull;
static constexpr unsigned long long OFF_COV  = OFF_XC   + 6400000ull;
static constexpr unsigned long long OFF_P    = OFF_COV  + 640000ull;
// G reuses the xc region (dead after k_cov): 16*10000 f32
static constexpr unsigned long long OFF_G    = OFF_XC;

struct PrepPtrs  { const float* w1[3]; const float* w2[3]; const float* w3[3]; const float* w4[3]; };
struct FrontPtrs { const float* g1[3]; const float* b1[3]; const float* w5[3];
                   const float* g2[3]; const float* b2[3]; int K[3]; };

__device__ __forceinline__ float block_sum(float v, float* sbuf) {
  #pragma unroll
  for (int off = 32; off > 0; off >>= 1) v += __shfl_down(v, off, 64);
  const int wid  = threadIdx.x >> 6;
  const int lane = threadIdx.x & 63;
  const int nw   = blockDim.x >> 6;
  if (lane == 0) sbuf[wid] = v;
  __syncthreads();
  float r = 0.f;
  for (int w = 0; w < nw; ++w) r += sbuf[w];
  __syncthreads();
  return r;
}

// DPP wave shifts: SHR1 -> dst[i]=src[i-1] (lane0 takes `old`);
//                  SHL1 -> dst[i]=src[i+1] (lane63 takes `old`).
__device__ __forceinline__ float dpp_shr1(float old_, float src) {
  return __builtin_bit_cast(float, __builtin_amdgcn_update_dpp(
      __builtin_bit_cast(int, old_), __builtin_bit_cast(int, src),
      0x138, 0xf, 0xf, false));
}
__device__ __forceinline__ float dpp_shl1(float old_, float src) {
  return __builtin_bit_cast(float, __builtin_amdgcn_update_dpp(
      __builtin_bit_cast(int, old_), __builtin_bit_cast(int, src),
      0x130, 0xf, 0xf, false));
}

// ---------------------------------------------------------------------------
// K1: fold conv(3,1) + w2-expand + max-norm depthwise spatial + pointwise
// ---------------------------------------------------------------------------
__global__ __launch_bounds__(256) void k_prep(PrepPtrs pp, float* __restrict__ M2) {
  const int beta = blockIdx.x;
  __shared__ float w3r[EXP_*CN_];
  __shared__ float M[FCH_*CN_];
  const float* w1 = pp.w1[beta];
  const float* w2 = pp.w2[beta];
  const float* w3 = pp.w3[beta];
  const float* w4 = pp.w4[beta];

  for (int g = threadIdx.x; g < EXP_; g += 256) {
    float s = 0.f;
    for (int c = 0; c < CN_; ++c) { float w = w3[g*CN_ + c]; s += w*w; }
    float n = sqrtf(s);
    float scale = fminf(1.f, 1.f/(n + 1e-12f)) * w2[g];
    for (int c = 0; c < CN_; ++c) w3r[g*CN_ + c] = w3[g*CN_ + c] * scale;
  }
  __syncthreads();
  for (int idx = threadIdx.x; idx < FCH_*CN_; idx += 256) {
    int o = idx / CN_, c = idx - o*CN_;
    float acc = 0.f;
    for (int g = 0; g < EXP_; ++g) acc += w4[o*EXP_ + g] * w3r[g*CN_ + c];
    M[idx] = acc;
  }
  __syncthreads();
  const float k0 = w1[0], k1 = w1[1], k2 = w1[2];
  for (int idx = threadIdx.x; idx < FCH_*CN_; idx += 256) {
    int c = idx % CN_;
    float v = k1 * M[idx];
    if (c > 0)       v += k2 * M[idx - 1];
    if (c < CN_ - 1) v += k0 * M[idx + 1];
    M2[beta*FCH_*CN_ + idx] = v;
  }
}

// ---------------------------------------------------------------------------
// K2: per (beta,b,o) row: h = M2 row @ x[b] -> LN -> depthwise conv K -> LN
// ---------------------------------------------------------------------------
__global__ __launch_bounds__(256) void k_front(const float* __restrict__ x,
                                               const float* __restrict__ M2,
                                               FrontPtrs fp,
                                               float* __restrict__ hcat) {
  const int wg   = blockIdx.x;
  const int beta = wg / (B_*FCH_);
  const int rem  = wg - beta*(B_*FCH_);
  const int b    = rem / FCH_;
  const int o    = rem - b*FCH_;
  const int K    = fp.K[beta];
  const int Kh   = K >> 1;

  __shared__ float m2[CN_];
  __shared__ float hb2[T_];
  __shared__ float w5s[80];
  __shared__ float red[8];

  if (threadIdx.x < CN_) m2[threadIdx.x] = M2[(beta*FCH_ + o)*CN_ + threadIdx.x];
  if (threadIdx.x < K)   w5s[threadIdx.x] = fp.w5[beta][o*K + threadIdx.x];
  __syncthreads();

  const float* xb = x + (size_t)b*CN_*T_;
  float hv[4];
  float psum = 0.f;
  #pragma unroll
  for (int e = 0; e < 4; ++e) {
    int t = threadIdx.x + 256*e;
    float acc = 0.f;
    if (t < T_) {
      #pragma unroll
      for (int c = 0; c < CN_; ++c) acc += m2[c] * xb[c*T_ + t];
    }
    hv[e] = acc; psum += acc;
  }
  float mean = block_sum(psum, red) * (1.f/T_);
  float pv = 0.f;
  #pragma unroll
  for (int e = 0; e < 4; ++e) { int t = threadIdx.x + 256*e; if (t < T_) { float d = hv[e]-mean; pv += d*d; } }
  float var = block_sum(pv, red) * (1.f/T_);
  float inv = rsqrtf(var + 1e-5f);
  const float* g1 = fp.g1[beta]; const float* b1 = fp.b1[beta];
  #pragma unroll
  for (int e = 0; e < 4; ++e) { int t = threadIdx.x + 256*e; if (t < T_) hb2[t] = (hv[e]-mean)*inv*g1[t] + b1[t]; }
  __syncthreads();

  float cv[4];
  float ps2 = 0.f;
  #pragma unroll
  for (int e = 0; e < 4; ++e) {
    int t = threadIdx.x + 256*e;
    float acc = 0.f;
    if (t < T_) {
      int lo = t - Kh;
      for (int k = 0; k < K; ++k) {
        int tt = lo + k;
        float hvv = (tt >= 0 && tt < T_) ? hb2[tt] : 0.f;
        acc += hvv * w5s[k];
      }
    }
    cv[e] = acc; ps2 += acc;
  }
  float mean2 = block_sum(ps2, red) * (1.f/T_);
  float pv2 = 0.f;
  #pragma unroll
  for (int e = 0; e < 4; ++e) { int t = threadIdx.x + 256*e; if (t < T_) { float d = cv[e]-mean2; pv2 += d*d; } }
  float var2 = block_sum(pv2, red) * (1.f/T_);
  float inv2 = rsqrtf(var2 + 1e-5f);
  const float* g2 = fp.g2[beta]; const float* b2 = fp.b2[beta];
  float* hrow = hcat + ((size_t)b*(3*FCH_) + beta*FCH_ + o)*T_;
  #pragma unroll
  for (int e = 0; e < 4; ++e) { int t = threadIdx.x + 256*e; if (t < T_) hrow[t] = (cv[e]-mean2)*inv2*g2[t] + b2[t]; }
}

// ---------------------------------------------------------------------------
// K3: h_s = w_sconv @ hcat per b, subtract per-row time mean, store xc.
// ---------------------------------------------------------------------------
__global__ __launch_bounds__(256) void k_sconv(const float* __restrict__ hcat,
                                               const float* __restrict__ wsc,
                                               float* __restrict__ xc) {
  const int b  = blockIdx.x / 10;
  const int s0 = (blockIdx.x % 10) * 10;
  __shared__ float ws[10*450];
  __shared__ float red[8];
  for (int idx = threadIdx.x; idx < 4500; idx += 256) {
    int s = idx / 450, i = idx - s*450;
    ws[idx] = wsc[(s0+s)*450 + i];
  }
  __syncthreads();
  float acc[10][4];
  #pragma unroll
  for (int s = 0; s < 10; ++s)
    #pragma unroll
    for (int e = 0; e < 4; ++e) acc[s][e] = 0.f;
  const float* hb = hcat + (size_t)b*450*T_;
  for (int i = 0; i < 450; ++i) {
    float xv[4];
    #pragma unroll
    for (int e = 0; e < 4; ++e) { int t = threadIdx.x + 256*e; xv[e] = (t < T_) ? hb[(size_t)i*T_ + t] : 0.f; }
    #pragma unroll
    for (int s = 0; s < 10; ++s) {
      float w = ws[s*450 + i];
      #pragma unroll
      for (int e = 0; e < 4; ++e) acc[s][e] += w * xv[e];
    }
  }
  for (int s = 0; s < 10; ++s) {
    float mu = block_sum(acc[s][0]+acc[s][1]+acc[s][2]+acc[s][3], red) * (1.f/T_);
    float* xr = xc + ((size_t)b*SPD_ + s0 + s)*T_;
    #pragma unroll
    for (int e = 0; e < 4; ++e) { int t = threadIdx.x + 256*e; if (t < T_) xr[t] = acc[s][e] - mu; }
  }
}

// ---------------------------------------------------------------------------
// K4a: cov = xc xc^T /999 + 1e-4 I
// ---------------------------------------------------------------------------
__global__ __launch_bounds__(256) void k_cov(const float* __restrict__ xc, float* __restrict__ cov) {
  const int b  = blockIdx.x / 5;
  const int j0 = (blockIdx.x % 5) * 20;
  __shared__ __align__(16) float xst[SPD_*100];
  const int it = threadIdx.x / 10;
  const int jj = threadIdx.x - it*10;
  const bool act = threadIdx.x < 250;
  double a64[4][2] = {{0.0,0.0},{0.0,0.0},{0.0,0.0},{0.0,0.0}};
  for (int ch = 0; ch < 10; ++ch) {
    __syncthreads();
    const int tc0 = ch*100;
    for (int idx = threadIdx.x; idx < SPD_*100; idx += 256) {
      int row = idx / 100, tt = idx - row*100;
      xst[idx] = xc[((size_t)b*SPD_ + row)*T_ + tc0 + tt];
    }
    __syncthreads();
    if (act) {
      float a32[4][2] = {{0,0},{0,0},{0,0},{0,0}};
      for (int t4 = 0; t4 < 100; t4 += 4) {
        float4 xi[4], xj[2];
        #pragma unroll
        for (int r = 0; r < 4; ++r) xi[r] = *(const float4*)&xst[(it + 25*r)*100 + t4];
        #pragma unroll
        for (int s = 0; s < 2; ++s) xj[s] = *(const float4*)&xst[(j0 + jj + 10*s)*100 + t4];
        #pragma unroll
        for (int r = 0; r < 4; ++r)
          #pragma unroll
          for (int s = 0; s < 2; ++s)
            a32[r][s] += xi[r].x*xj[s].x + xi[r].y*xj[s].y + xi[r].z*xj[s].z + xi[r].w*xj[s].w;
      }
      #pragma unroll
      for (int r = 0; r < 4; ++r)
        #pragma unroll
        for (int s = 0; s < 2; ++s) a64[r][s] += (double)a32[r][s];
    }
  }
  if (act) {
    #pragma unroll
    for (int r = 0; r < 4; ++r) {
      #pragma unroll
      for (int s = 0; s < 2; ++s) {
        int i = it + 25*r, j = j0 + jj + 10*s;
        double v = a64[r][s] * (1.0/999.0);
        if (i == j) v += 1e-4;
        cov[(size_t)b*SPD_*SPD_ + i*SPD_ + j] = (float)v;
      }
    }
  }
}

// ---------------------------------------------------------------------------
// K4b (fused aff1+aff2): T1-tile = C @ W^T (kept in LDS), then P = W @ T1-tile.
// ---------------------------------------------------------------------------
__global__ __launch_bounds__(256) void k_aff(const float* __restrict__ cov,
                                             const float* __restrict__ waff,
                                             float* __restrict__ P) {
  const int b  = blockIdx.x / 5;
  const int j0 = (blockIdx.x % 5) * 20;
  __shared__ float Cs[SPD_*101];
  __shared__ float Ws[20*100];
  __shared__ float T1s[100*20];
  for (int idx = threadIdx.x; idx < SPD_*SPD_; idx += 256) {
    int r = idx / 100, c = idx - r*100;
    Cs[r*101 + c] = cov[(size_t)b*SPD_*SPD_ + idx];
  }
  for (int idx = threadIdx.x; idx < 2000; idx += 256) {
    int jl = idx / 100, k = idx - jl*100;
    Ws[idx] = waff[(j0+jl)*100 + k];
  }
  __syncthreads();
  const int it = threadIdx.x / 10, jj = threadIdx.x % 10;
  const bool act = threadIdx.x < 250;
  if (act) {
    double acc[4][2] = {{0.0,0.0},{0.0,0.0},{0.0,0.0},{0.0,0.0}};
    for (int k = 0; k < 100; ++k) {
      double cvv[4], wv[2];
      #pragma unroll
      for (int r = 0; r < 4; ++r) cvv[r] = (double)Cs[(it + 25*r)*101 + k];
      #pragma unroll
      for (int s = 0; s < 2; ++s) wv[s] = (double)Ws[(jj + 10*s)*100 + k];
      #pragma unroll
      for (int r = 0; r < 4; ++r)
        #pragma unroll
        for (int s = 0; s < 2; ++s) acc[r][s] += cvv[r]*wv[s];
    }
    #pragma unroll
    for (int r = 0; r < 4; ++r)
      #pragma unroll
      for (int s = 0; s < 2; ++s)
        T1s[(it + 25*r)*20 + (jj + 10*s)] = (float)acc[r][s];
  }
  __syncthreads();
  if (act) {
    double acc[4][2] = {{0.0,0.0},{0.0,0.0},{0.0,0.0},{0.0,0.0}};
    for (int k = 0; k < 100; ++k) {
      double wv[4], tv[2];
      #pragma unroll
      for (int r = 0; r < 4; ++r) wv[r] = (double)waff[(it + 25*r)*100 + k];
      #pragma unroll
      for (int s = 0; s < 2; ++s) tv[s] = (double)T1s[k*20 + jj + 10*s];
      #pragma unroll
      for (int r = 0; r < 4; ++r)
        #pragma unroll
        for (int s = 0; s < 2; ++s) acc[r][s] += wv[r]*tv[s];
    }
    #pragma unroll
    for (int r = 0; r < 4; ++r)
      #pragma unroll
      for (int s = 0; s < 2; ++s)
        P[(size_t)b*SPD_*SPD_ + (it + 25*r)*100 + (j0 + jj + 10*s)] = (float)acc[r][s];
  }
}

// ---------------------------------------------------------------------------
// K5: register-resident systolic one-sided Jacobi, DPP migration, packed-fp32.
// TWO waves per matrix (128 thr): lane holds 50 rows = exactly 25 float2 (no
// scalar tail). Rationale (round-12 post-mortem): per-wave issue is only
// ~340 cyc of the ~1600-cyc round — the residue is the cross-wave reduction
// (ds_write -> 4-wave barrier -> conflicted b128 read -> sum -> serial
// decision). Halving waves doubles per-wave issue (~700 cyc) but shrinks the
// sync: 2 partials (b64), 2-wave barrier. Phase-separated in 5-v2f chunks.
// ---------------------------------------------------------------------------
__global__ __launch_bounds__(128)
__attribute__((amdgpu_waves_per_eu(1, 1)))
void k_eig(const float* __restrict__ P, float* __restrict__ Gout) {
  __shared__ __align__(16) float gbuf[2][128];
  __shared__ __align__(16) float nbuf[256];
  const int tid = threadIdx.x;
  const int b   = blockIdx.x;
  const int w   = tid >> 6;            // 0 or 1: row half
  const int j   = tid & 63;
  const bool act = (j < 50);
  const int rb  = 50 * w;

  v2f A2[25], B2[25];
  const float* Pb = P + (size_t)b*SPD_*SPD_;
  #pragma unroll
  for (int i = 0; i < 25; ++i) {
    A2[i].x = act ? Pb[(rb+2*i  )*SPD_ + j]      : 0.f;
    A2[i].y = act ? Pb[(rb+2*i+1)*SPD_ + j]      : 0.f;
    B2[i].x = act ? Pb[(rb+2*i  )*SPD_ + (99-j)] : 0.f;
    B2[i].y = act ? Pb[(rb+2*i+1)*SPD_ + (99-j)] : 0.f;
  }

  {
    v2f pA2 = {0.f, 0.f}, pB2 = {0.f, 0.f};
    #pragma unroll
    for (int i = 0; i < 25; ++i) { pA2 += A2[i]*A2[i]; pB2 += B2[i]*B2[i]; }
    nbuf[j*4 + w*2 + 0] = pA2.x + pA2.y;
    nbuf[j*4 + w*2 + 1] = pB2.x + pB2.y;
  }
  __syncthreads();
  float nA, nB;
  {
    float4 u = *(const float4*)&nbuf[j*4];
    nA = u.x + u.z;
    nB = u.y + u.w;
  }
  float pg;
  {
    v2f pg2 = {0.f, 0.f};
    #pragma unroll
    for (int i = 0; i < 25; ++i) pg2 += A2[i]*B2[i];
    pg = pg2.x + pg2.y;
  }

  int par = 0;
  for (int sweep = 0; sweep < NSWEEP; ++sweep) {
    for (int r = 0; r < 99; ++r) {
      gbuf[par][j*2 + w] = pg;
      __syncthreads();                       // the ONLY barrier per round
      v2f gp = *(const v2f*)&gbuf[par][j*2];
      float gamma = gp.x + gp.y;

      // branchless rotation decision (identity when below threshold / idle)
      float g2v = gamma*gamma;
      float ab = nA*nB;
      float tau = (g2v > 1e-12f*ab) ? ((nB - nA) / (2.f*gamma)) : 1e30f;
      float t  = ((tau >= 0.f) ? 1.f : -1.f) / (fabsf(tau) + sqrtf(1.f + tau*tau));
      float cr = rsqrtf(1.f + t*t);
      float sr = t*cr;
      nA = nA - t*gamma;
      nB = nB + t*gamma;

      // norm migration (DPP)
      {
        float sendN = (j == 0) ? nB : nA;
        float rNA = dpp_shr1(nA, sendN);     // lane0 keeps old nA
        float rNB = dpp_shl1(nB, nB);        // lane63 keeps old (garbage ok)
        float newB = (j == 49) ? nA : rNB;
        nA = rNA; nB = newB;
      }

      const v2f cr2 = {cr, cr};
      const v2f sr2 = {sr, sr};
      v2f pg2 = {0.f, 0.f};
      // chunked phase separation: 5 chunks x 5 v2f (bounds temps ~50 regs,
      // keeps >=20 instrs between a DPP and its source write)
      #pragma unroll
      for (int c = 0; c < 5; ++c) {
        const int base = c*5;
        v2f na[5], nb[5], sa[5], rA[5], rB[5];
        #pragma unroll
        for (int i = 0; i < 5; ++i) {
          na[i] = cr2*A2[base+i] - sr2*B2[base+i];
          nb[i] = sr2*A2[base+i] + cr2*B2[base+i];
        }
        #pragma unroll
        for (int i = 0; i < 5; ++i) {
          sa[i].x = (j == 0) ? nb[i].x : na[i].x;
          sa[i].y = (j == 0) ? nb[i].y : na[i].y;
        }
        #pragma unroll
        for (int i = 0; i < 5; ++i) {
          rA[i].x = dpp_shr1(na[i].x, sa[i].x);  // lane0 keeps na
          rA[i].y = dpp_shr1(na[i].y, sa[i].y);
          rB[i].x = dpp_shl1(nb[i].x, nb[i].x);
          rB[i].y = dpp_shl1(nb[i].y, nb[i].y);
        }
        #pragma unroll
        for (int i = 0; i < 5; ++i) {
          A2[base+i] = rA[i];
          B2[base+i].x = (j == 49) ? na[i].x : rB[i].x;
          B2[base+i].y = (j == 49) ? na[i].y : rB[i].y;
          pg2 += A2[base+i]*B2[base+i];
        }
      }
      pg = pg2.x + pg2.y;
      par ^= 1;
    }
  }

  // dump columns straight to workspace (col-major per matrix, stride 100)
  if (act) {
    float* Gb = Gout + (size_t)b*SPD_*SPD_;
    #pragma unroll
    for (int i = 0; i < 25; ++i) {
      Gb[j*SPD_ + rb + 2*i]   = A2[i].x;
      Gb[j*SPD_ + rb + 2*i+1] = A2[i].y;
      Gb[(50 + j)*SPD_ + rb + 2*i]   = B2[i].x;
      Gb[(50 + j)*SPD_ + rb + 2*i+1] = B2[i].y;
    }
  }
}

// ---------------------------------------------------------------------------
// K5b (merged with FC): per-column fp64 norms -> wc = log(clip(lam,1e-6))/lam^2,
// L = sum_c wc[c] g_c g_c^T -> scaled upper-tri flat -> out[64 + b*5050 + idx],
// and logits = flat @ w_fc^T + b_fc accumulated in the same pass.
// ---------------------------------------------------------------------------
__global__ __launch_bounds__(256) void k_lout(const float* __restrict__ Gin,
                                              const float* __restrict__ wfc,
                                              const float* __restrict__ bfc,
                                              float* __restrict__ out) {
  __shared__ __align__(16) float G[SPD_*SPD_];
  __shared__ float wcs[SPD_];
  __shared__ float red[8];
  const int tid = threadIdx.x;
  const int b   = blockIdx.x;
  for (int idx = tid; idx < SPD_*SPD_; idx += 256)
    G[idx] = Gin[(size_t)b*SPD_*SPD_ + idx];
  __syncthreads();
  if (tid < SPD_) {
    const float* col = &G[tid*SPD_];
    double s = 0.0;
    for (int i = 0; i < SPD_; ++i) { double v = (double)col[i]; s += v*v; }
    double lam = sqrt(s);
    double lc  = (lam < 1e-6) ? 1e-6 : lam;
    wcs[tid] = (float)(log(lc) / ((s > 1e-300) ? s : 1e-300));
  }
  __syncthreads();

  float a0 = 0.f, a1 = 0.f, a2 = 0.f, a3 = 0.f;
  for (int tile = tid; tile < 625; tile += 256) {
    const int ti = (tile / 25) * 4;
    const int tj = (tile % 25) * 4;
    float acc[4][4];
    #pragma unroll
    for (int r = 0; r < 4; ++r)
      #pragma unroll
      for (int s = 0; s < 4; ++s) acc[r][s] = 0.f;
    for (int c = 0; c < SPD_; ++c) {
      const float* col = &G[c*SPD_];
      float4 ga = *(const float4*)&col[ti];
      float4 gb = *(const float4*)&col[tj];
      float wcv = wcs[c];
      float wa[4] = { wcv*ga.x, wcv*ga.y, wcv*ga.z, wcv*ga.w };
      float bv[4] = { gb.x, gb.y, gb.z, gb.w };
      #pragma unroll
      for (int r = 0; r < 4; ++r)
        #pragma unroll
        for (int s = 0; s < 4; ++s) acc[r][s] += wa[r]*bv[s];
    }
    const float RT2 = 1.41421356237309505f;
    #pragma unroll
    for (int r = 0; r < 4; ++r) {
      #pragma unroll
      for (int s = 0; s < 4; ++s) {
        int i = ti + r, jx = tj + s;
        if (i <= jx) {
          int idx = i*SPD_ - (i*(i+1))/2 + jx;
          float val = acc[r][s] * (i == jx ? 1.f : RT2);
          out[64 + b*5050 + idx] = val;
          a0 += val * wfc[idx];
          a1 += val * wfc[5050 + idx];
          a2 += val * wfc[10100 + idx];
          a3 += val * wfc[15150 + idx];
        }
      }
    }
  }
  a0 = block_sum(a0, red);
  a1 = block_sum(a1, red);
  a2 = block_sum(a2, red);
  a3 = block_sum(a3, red);
  if (tid == 0) {
    out[b*4 + 0] = a0 + bfc[0];
    out[b*4 + 1] = a1 + bfc[1];
    out[b*4 + 2] = a2 + bfc[2];
    out[b*4 + 3] = a3 + bfc[3];
  }
}

extern "C" void kernel_launch(void* const* d_in, const int* in_sizes, int n_in,
                              void* d_out, int out_size, void* d_ws, size_t ws_size,
                              hipStream_t stream) {
  (void)in_sizes; (void)n_in; (void)out_size; (void)ws_size;
  const float* x = (const float*)d_in[0];
  const float* bw[3][9];
  for (int i = 0; i < 3; ++i)
    for (int jx = 0; jx < 9; ++jx)
      bw[i][jx] = (const float*)d_in[1 + i*9 + jx];
  const float* w_sconv = (const float*)d_in[28];
  const float* w_aff   = (const float*)d_in[29];
  const float* w_fc    = (const float*)d_in[30];
  const float* b_fc    = (const float*)d_in[31];

  char* ws = (char*)d_ws;
  float*  M2   = (float*)(ws + OFF_M2);
  float*  hcat = (float*)(ws + OFF_HCAT);
  float*  xc   = (float*)(ws + OFF_XC);
  float*  cov  = (float*)(ws + OFF_COV);
  float*  P    = (float*)(ws + OFF_P);
  float*  G    = (float*)(ws + OFF_G);    // reuses xc region (dead after k_cov)
  float*  out  = (float*)d_out;

  PrepPtrs pp; FrontPtrs fp;
  for (int i = 0; i < 3; ++i) {
    pp.w1[i] = bw[i][0]; pp.w2[i] = bw[i][1]; pp.w3[i] = bw[i][2]; pp.w4[i] = bw[i][3];
    fp.g1[i] = bw[i][4]; fp.b1[i] = bw[i][5]; fp.w5[i] = bw[i][6];
    fp.g2[i] = bw[i][7]; fp.b2[i] = bw[i][8];
  }
  fp.K[0] = 15; fp.K[1] = 75; fp.K[2] = 55;

  hipLaunchKernelGGL(k_prep,  dim3(3),            dim3(256), 0, stream, pp, M2);
  hipLaunchKernelGGL(k_front, dim3(3*B_*FCH_),    dim3(256), 0, stream, x, M2, fp, hcat);
  hipLaunchKernelGGL(k_sconv, dim3(B_*10),        dim3(256), 0, stream, hcat, w_sconv, xc);
  hipLaunchKernelGGL(k_cov,   dim3(B_*5),         dim3(256), 0, stream, xc, cov);
  hipLaunchKernelGGL(k_aff,   dim3(B_*5),         dim3(256), 0, stream, cov, w_aff, P);
  hipLaunchKernelGGL(k_eig,   dim3(B_),           dim3(128), 0, stream, P, G);
  hipLaunchKernelGGL(k_lout,  dim3(B_),           dim3(256), 0, stream, G, w_fc, b_fc, out);
}

// Round 14
// 1042.992 us; speedup vs baseline: 1.2395x; 1.2395x over previous
//
#include <hip/hip_runtime.h>

#define B_ 16
#define CN_ 22
#define T_ 1000
#define EXP_ 300
#define FCH_ 150
#define SPD_ 100
#define NSWEEP 8

typedef float v2f __attribute__((ext_vector_type(2)));

// workspace layout (bytes)
static constexpr unsigned long long OFF_HCAT = 65536ull;
static constexpr unsigned long long OFF_XC   = OFF_HCAT + 28800000ull;
static constexpr unsigned long long OFF_COV  = OFF_XC   + 6400000ull;
static constexpr unsigned long long OFF_P    = OFF_COV  + 640000ull;
// G reuses the xc region (dead after k_cov): 16*10000 f32
static constexpr unsigned long long OFF_G    = OFF_XC;

struct PrepPtrs  { const float* w1[3]; const float* w2[3]; const float* w3[3]; const float* w4[3]; };
struct FrontPtrs { const float* g1[3]; const float* b1[3]; const float* w5[3];
                   const float* g2[3]; const float* b2[3]; int K[3]; };

__device__ __forceinline__ float block_sum(float v, float* sbuf) {
  #pragma unroll
  for (int off = 32; off > 0; off >>= 1) v += __shfl_down(v, off, 64);
  const int wid  = threadIdx.x >> 6;
  const int lane = threadIdx.x & 63;
  const int nw   = blockDim.x >> 6;
  if (lane == 0) sbuf[wid] = v;
  __syncthreads();
  float r = 0.f;
  for (int w = 0; w < nw; ++w) r += sbuf[w];
  __syncthreads();
  return r;
}

// DPP wave shifts: SHR1 -> dst[i]=src[i-1] (lane0 takes `old`);
//                  SHL1 -> dst[i]=src[i+1] (lane63 takes `old`).
__device__ __forceinline__ float dpp_shr1(float old_, float src) {
  return __builtin_bit_cast(float, __builtin_amdgcn_update_dpp(
      __builtin_bit_cast(int, old_), __builtin_bit_cast(int, src),
      0x138, 0xf, 0xf, false));
}
__device__ __forceinline__ float dpp_shl1(float old_, float src) {
  return __builtin_bit_cast(float, __builtin_amdgcn_update_dpp(
      __builtin_bit_cast(int, old_), __builtin_bit_cast(int, src),
      0x130, 0xf, 0xf, false));
}

// ---------------------------------------------------------------------------
// K2 (k_prep folded in): per (beta,b,o) block compute its own M2 row in LDS
// (norms + w2/max-norm fold + pointwise row + conv(3,1) fold), then
// h = m2 @ x[b] -> LN -> depthwise conv K -> LN.
// ---------------------------------------------------------------------------
__global__ __launch_bounds__(256) void k_front(const float* __restrict__ x,
                                               PrepPtrs pp,
                                               FrontPtrs fp,
                                               float* __restrict__ hcat) {
  const int wg   = blockIdx.x;
  const int beta = wg / (B_*FCH_);
  const int rem  = wg - beta*(B_*FCH_);
  const int b    = rem / FCH_;
  const int o    = rem - b*FCH_;
  const int K    = fp.K[beta];
  const int Kh   = K >> 1;

  __shared__ float scale[EXP_];
  __shared__ float mpart[220];
  __shared__ float mrow[CN_];
  __shared__ float m2[CN_];
  __shared__ float hb2[T_];
  __shared__ float w5s[80];
  __shared__ float red[8];

  const float* w1 = pp.w1[beta];
  const float* w2 = pp.w2[beta];
  const float* w3 = pp.w3[beta];
  const float* w4 = pp.w4[beta];

  // per-g max-norm scale * w2
  for (int g = threadIdx.x; g < EXP_; g += 256) {
    float s = 0.f;
    for (int c = 0; c < CN_; ++c) { float wv = w3[g*CN_ + c]; s += wv*wv; }
    scale[g] = fminf(1.f, 1.f/(sqrtf(s) + 1e-12f)) * w2[g];
  }
  if (threadIdx.x < K) w5s[threadIdx.x] = fp.w5[beta][o*K + threadIdx.x];
  __syncthreads();
  // Mrow[c] = sum_g w4[o,g]*scale[g]*w3[g,c], chunked 10x30 per c
  if (threadIdx.x < 220) {
    const int c = threadIdx.x / 10, part = threadIdx.x % 10;
    float acc = 0.f;
    const int g0 = part*30;
    for (int g = g0; g < g0+30; ++g) acc += w4[o*EXP_ + g] * scale[g] * w3[g*CN_ + c];
    mpart[threadIdx.x] = acc;
  }
  __syncthreads();
  if (threadIdx.x < CN_) {
    float acc = 0.f;
    for (int p = 0; p < 10; ++p) acc += mpart[threadIdx.x*10 + p];
    mrow[threadIdx.x] = acc;
  }
  __syncthreads();
  if (threadIdx.x < CN_) {
    const int c = threadIdx.x;
    float v = w1[1] * mrow[c];
    if (c > 0)       v += w1[2] * mrow[c - 1];
    if (c < CN_ - 1) v += w1[0] * mrow[c + 1];
    m2[c] = v;
  }
  __syncthreads();

  const float* xb = x + (size_t)b*CN_*T_;
  float hv[4];
  float psum = 0.f;
  #pragma unroll
  for (int e = 0; e < 4; ++e) {
    int t = threadIdx.x + 256*e;
    float acc = 0.f;
    if (t < T_) {
      #pragma unroll
      for (int c = 0; c < CN_; ++c) acc += m2[c] * xb[c*T_ + t];
    }
    hv[e] = acc; psum += acc;
  }
  float mean = block_sum(psum, red) * (1.f/T_);
  float pv = 0.f;
  #pragma unroll
  for (int e = 0; e < 4; ++e) { int t = threadIdx.x + 256*e; if (t < T_) { float d = hv[e]-mean; pv += d*d; } }
  float var = block_sum(pv, red) * (1.f/T_);
  float inv = rsqrtf(var + 1e-5f);
  const float* g1 = fp.g1[beta]; const float* b1 = fp.b1[beta];
  #pragma unroll
  for (int e = 0; e < 4; ++e) { int t = threadIdx.x + 256*e; if (t < T_) hb2[t] = (hv[e]-mean)*inv*g1[t] + b1[t]; }
  __syncthreads();

  float cv[4];
  float ps2 = 0.f;
  #pragma unroll
  for (int e = 0; e < 4; ++e) {
    int t = threadIdx.x + 256*e;
    float acc = 0.f;
    if (t < T_) {
      int lo = t - Kh;
      for (int k = 0; k < K; ++k) {
        int tt = lo + k;
        float hvv = (tt >= 0 && tt < T_) ? hb2[tt] : 0.f;
        acc += hvv * w5s[k];
      }
    }
    cv[e] = acc; ps2 += acc;
  }
  float mean2 = block_sum(ps2, red) * (1.f/T_);
  float pv2 = 0.f;
  #pragma unroll
  for (int e = 0; e < 4; ++e) { int t = threadIdx.x + 256*e; if (t < T_) { float d = cv[e]-mean2; pv2 += d*d; } }
  float var2 = block_sum(pv2, red) * (1.f/T_);
  float inv2 = rsqrtf(var2 + 1e-5f);
  const float* g2 = fp.g2[beta]; const float* b2 = fp.b2[beta];
  float* hrow = hcat + ((size_t)b*(3*FCH_) + beta*FCH_ + o)*T_;
  #pragma unroll
  for (int e = 0; e < 4; ++e) { int t = threadIdx.x + 256*e; if (t < T_) hrow[t] = (cv[e]-mean2)*inv2*g2[t] + b2[t]; }
}

// ---------------------------------------------------------------------------
// K3: h_s = w_sconv @ hcat per b, subtract per-row time mean, store xc.
// ---------------------------------------------------------------------------
__global__ __launch_bounds__(256) void k_sconv(const float* __restrict__ hcat,
                                               const float* __restrict__ wsc,
                                               float* __restrict__ xc) {
  const int b  = blockIdx.x / 10;
  const int s0 = (blockIdx.x % 10) * 10;
  __shared__ float ws[10*450];
  __shared__ float red[8];
  for (int idx = threadIdx.x; idx < 4500; idx += 256) {
    int s = idx / 450, i = idx - s*450;
    ws[idx] = wsc[(s0+s)*450 + i];
  }
  __syncthreads();
  float acc[10][4];
  #pragma unroll
  for (int s = 0; s < 10; ++s)
    #pragma unroll
    for (int e = 0; e < 4; ++e) acc[s][e] = 0.f;
  const float* hb = hcat + (size_t)b*450*T_;
  for (int i = 0; i < 450; ++i) {
    float xv[4];
    #pragma unroll
    for (int e = 0; e < 4; ++e) { int t = threadIdx.x + 256*e; xv[e] = (t < T_) ? hb[(size_t)i*T_ + t] : 0.f; }
    #pragma unroll
    for (int s = 0; s < 10; ++s) {
      float w = ws[s*450 + i];
      #pragma unroll
      for (int e = 0; e < 4; ++e) acc[s][e] += w * xv[e];
    }
  }
  for (int s = 0; s < 10; ++s) {
    float mu = block_sum(acc[s][0]+acc[s][1]+acc[s][2]+acc[s][3], red) * (1.f/T_);
    float* xr = xc + ((size_t)b*SPD_ + s0 + s)*T_;
    #pragma unroll
    for (int e = 0; e < 4; ++e) { int t = threadIdx.x + 256*e; if (t < T_) xr[t] = acc[s][e] - mu; }
  }
}

// ---------------------------------------------------------------------------
// K4a: cov = xc xc^T /999 + 1e-4 I
// ---------------------------------------------------------------------------
__global__ __launch_bounds__(256) void k_cov(const float* __restrict__ xc, float* __restrict__ cov) {
  const int b  = blockIdx.x / 5;
  const int j0 = (blockIdx.x % 5) * 20;
  __shared__ __align__(16) float xst[SPD_*100];
  const int it = threadIdx.x / 10;
  const int jj = threadIdx.x - it*10;
  const bool act = threadIdx.x < 250;
  double a64[4][2] = {{0.0,0.0},{0.0,0.0},{0.0,0.0},{0.0,0.0}};
  for (int ch = 0; ch < 10; ++ch) {
    __syncthreads();
    const int tc0 = ch*100;
    for (int idx = threadIdx.x; idx < SPD_*100; idx += 256) {
      int row = idx / 100, tt = idx - row*100;
      xst[idx] = xc[((size_t)b*SPD_ + row)*T_ + tc0 + tt];
    }
    __syncthreads();
    if (act) {
      float a32[4][2] = {{0,0},{0,0},{0,0},{0,0}};
      for (int t4 = 0; t4 < 100; t4 += 4) {
        float4 xi[4], xj[2];
        #pragma unroll
        for (int r = 0; r < 4; ++r) xi[r] = *(const float4*)&xst[(it + 25*r)*100 + t4];
        #pragma unroll
        for (int s = 0; s < 2; ++s) xj[s] = *(const float4*)&xst[(j0 + jj + 10*s)*100 + t4];
        #pragma unroll
        for (int r = 0; r < 4; ++r)
          #pragma unroll
          for (int s = 0; s < 2; ++s)
            a32[r][s] += xi[r].x*xj[s].x + xi[r].y*xj[s].y + xi[r].z*xj[s].z + xi[r].w*xj[s].w;
      }
      #pragma unroll
      for (int r = 0; r < 4; ++r)
        #pragma unroll
        for (int s = 0; s < 2; ++s) a64[r][s] += (double)a32[r][s];
    }
  }
  if (act) {
    #pragma unroll
    for (int r = 0; r < 4; ++r) {
      #pragma unroll
      for (int s = 0; s < 2; ++s) {
        int i = it + 25*r, j = j0 + jj + 10*s;
        double v = a64[r][s] * (1.0/999.0);
        if (i == j) v += 1e-4;
        cov[(size_t)b*SPD_*SPD_ + i*SPD_ + j] = (float)v;
      }
    }
  }
}

// ---------------------------------------------------------------------------
// K4b (fused aff1+aff2): T1-tile = C @ W^T (kept in LDS), then P = W @ T1-tile.
// ---------------------------------------------------------------------------
__global__ __launch_bounds__(256) void k_aff(const float* __restrict__ cov,
                                             const float* __restrict__ waff,
                                             float* __restrict__ P) {
  const int b  = blockIdx.x / 5;
  const int j0 = (blockIdx.x % 5) * 20;
  __shared__ float Cs[SPD_*101];
  __shared__ float Ws[20*100];
  __shared__ float T1s[100*20];
  for (int idx = threadIdx.x; idx < SPD_*SPD_; idx += 256) {
    int r = idx / 100, c = idx - r*100;
    Cs[r*101 + c] = cov[(size_t)b*SPD_*SPD_ + idx];
  }
  for (int idx = threadIdx.x; idx < 2000; idx += 256) {
    int jl = idx / 100, k = idx - jl*100;
    Ws[idx] = waff[(j0+jl)*100 + k];
  }
  __syncthreads();
  const int it = threadIdx.x / 10, jj = threadIdx.x % 10;
  const bool act = threadIdx.x < 250;
  if (act) {
    double acc[4][2] = {{0.0,0.0},{0.0,0.0},{0.0,0.0},{0.0,0.0}};
    for (int k = 0; k < 100; ++k) {
      double cvv[4], wv[2];
      #pragma unroll
      for (int r = 0; r < 4; ++r) cvv[r] = (double)Cs[(it + 25*r)*101 + k];
      #pragma unroll
      for (int s = 0; s < 2; ++s) wv[s] = (double)Ws[(jj + 10*s)*100 + k];
      #pragma unroll
      for (int r = 0; r < 4; ++r)
        #pragma unroll
        for (int s = 0; s < 2; ++s) acc[r][s] += cvv[r]*wv[s];
    }
    #pragma unroll
    for (int r = 0; r < 4; ++r)
      #pragma unroll
      for (int s = 0; s < 2; ++s)
        T1s[(it + 25*r)*20 + (jj + 10*s)] = (float)acc[r][s];
  }
  __syncthreads();
  if (act) {
    double acc[4][2] = {{0.0,0.0},{0.0,0.0},{0.0,0.0},{0.0,0.0}};
    for (int k = 0; k < 100; ++k) {
      double wv[4], tv[2];
      #pragma unroll
      for (int r = 0; r < 4; ++r) wv[r] = (double)waff[(it + 25*r)*100 + k];
      #pragma unroll
      for (int s = 0; s < 2; ++s) tv[s] = (double)T1s[k*20 + jj + 10*s];
      #pragma unroll
      for (int r = 0; r < 4; ++r)
        #pragma unroll
        for (int s = 0; s < 2; ++s) acc[r][s] += wv[r]*tv[s];
    }
    #pragma unroll
    for (int r = 0; r < 4; ++r)
      #pragma unroll
      for (int s = 0; s < 2; ++s)
        P[(size_t)b*SPD_*SPD_ + (it + 25*r)*100 + (j0 + jj + 10*s)] = (float)acc[r][s];
  }
}

// ---------------------------------------------------------------------------
// K5: register-resident systolic one-sided Jacobi — EXACT round-12 kernel
// (known 528 us). 4 waves/matrix is the measured optimum of the issue-vs-sync
// trade: 8-wave dual-matrix (r8) and 2-wave (r13) both regressed. Packed-fp32
// rotate, phase-separated, DPP migration, fixed 8 sweeps (7 fails).
// ---------------------------------------------------------------------------
__global__ __launch_bounds__(256)
__attribute__((amdgpu_waves_per_eu(1, 1)))
void k_eig(const float* __restrict__ P, float* __restrict__ Gout) {
  __shared__ __align__(16) float gbuf[2][256];
  __shared__ __align__(16) float nbuf[512];
  const int tid = threadIdx.x;
  const int b   = blockIdx.x;
  const int w   = tid >> 6;
  const int j   = tid & 63;
  const bool act = (j < 50);
  const int rb  = 25 * w;

  v2f A2[12], B2[12];
  float As, Bs;   // row element 24
  const float* Pb = P + (size_t)b*SPD_*SPD_;
  #pragma unroll
  for (int i = 0; i < 12; ++i) {
    A2[i].x = act ? Pb[(rb+2*i  )*SPD_ + j]      : 0.f;
    A2[i].y = act ? Pb[(rb+2*i+1)*SPD_ + j]      : 0.f;
    B2[i].x = act ? Pb[(rb+2*i  )*SPD_ + (99-j)] : 0.f;
    B2[i].y = act ? Pb[(rb+2*i+1)*SPD_ + (99-j)] : 0.f;
  }
  As = act ? Pb[(rb+24)*SPD_ + j]      : 0.f;
  Bs = act ? Pb[(rb+24)*SPD_ + (99-j)] : 0.f;

  {
    v2f pA2 = {0.f, 0.f}, pB2 = {0.f, 0.f};
    #pragma unroll
    for (int i = 0; i < 12; ++i) { pA2 += A2[i]*A2[i]; pB2 += B2[i]*B2[i]; }
    nbuf[j*8 + w*2 + 0] = pA2.x + pA2.y + As*As;
    nbuf[j*8 + w*2 + 1] = pB2.x + pB2.y + Bs*Bs;
  }
  __syncthreads();
  float nA, nB;
  {
    float4 u0 = *(const float4*)&nbuf[j*8];
    float4 u1 = *(const float4*)&nbuf[j*8+4];
    nA = (u0.x + u0.z) + (u1.x + u1.z);
    nB = (u0.y + u0.w) + (u1.y + u1.w);
  }
  float pg;
  {
    v2f pg2 = {0.f, 0.f};
    #pragma unroll
    for (int i = 0; i < 12; ++i) pg2 += A2[i]*B2[i];
    pg = pg2.x + pg2.y + As*Bs;
  }

  int par = 0;
  for (int sweep = 0; sweep < NSWEEP; ++sweep) {
    for (int r = 0; r < 99; ++r) {
      gbuf[par][j*4 + w] = pg;
      __syncthreads();                       // the ONLY barrier per round
      float4 gp = *(const float4*)&gbuf[par][j*4];
      float gamma = (gp.x + gp.y) + (gp.z + gp.w);

      // branchless rotation decision (identity when below threshold / idle)
      float g2v = gamma*gamma;
      float ab = nA*nB;
      float tau = (g2v > 1e-12f*ab) ? ((nB - nA) / (2.f*gamma)) : 1e30f;
      float t  = ((tau >= 0.f) ? 1.f : -1.f) / (fabsf(tau) + sqrtf(1.f + tau*tau));
      float cr = rsqrtf(1.f + t*t);
      float sr = t*cr;
      nA = nA - t*gamma;
      nB = nB + t*gamma;

      // norm migration (DPP)
      {
        float sendN = (j == 0) ? nB : nA;
        float rNA = dpp_shr1(nA, sendN);     // lane0 keeps old nA
        float rNB = dpp_shl1(nB, nB);        // lane63 keeps old (garbage ok)
        float newB = (j == 49) ? nA : rNB;
        nA = rNA; nB = newB;
      }

      const v2f cr2 = {cr, cr};
      const v2f sr2 = {sr, sr};
      v2f na[12], nb[12], sa[12], rA[12], rB[12];
      float nas, nbs, sas, rAs, rBs;

      // Phase A: all rotation arithmetic (packed, independent)
      #pragma unroll
      for (int i = 0; i < 12; ++i) {
        na[i] = cr2*A2[i] - sr2*B2[i];
        nb[i] = sr2*A2[i] + cr2*B2[i];
      }
      nas = cr*As - sr*Bs;
      nbs = sr*As + cr*Bs;

      // Phase B: all send selects
      #pragma unroll
      for (int i = 0; i < 12; ++i) {
        sa[i].x = (j == 0) ? nb[i].x : na[i].x;
        sa[i].y = (j == 0) ? nb[i].y : na[i].y;
      }
      sas = (j == 0) ? nbs : nas;

      // Phase C: all DPPs (sources written many instrs earlier -> no hazard)
      #pragma unroll
      for (int i = 0; i < 12; ++i) {
        rA[i].x = dpp_shr1(na[i].x, sa[i].x);  // lane0 keeps na
        rA[i].y = dpp_shr1(na[i].y, sa[i].y);
        rB[i].x = dpp_shl1(nb[i].x, nb[i].x);
        rB[i].y = dpp_shl1(nb[i].y, nb[i].y);
      }
      rAs = dpp_shr1(nas, sas);
      rBs = dpp_shl1(nbs, nbs);

      // Phase D: final selects + next-round partial gamma
      v2f pg2 = {0.f, 0.f};
      #pragma unroll
      for (int i = 0; i < 12; ++i) {
        A2[i] = rA[i];
        B2[i].x = (j == 49) ? na[i].x : rB[i].x;
        B2[i].y = (j == 49) ? na[i].y : rB[i].y;
        pg2 += A2[i]*B2[i];
      }
      As = rAs;
      Bs = (j == 49) ? nas : rBs;
      pg = pg2.x + pg2.y + As*Bs;
      par ^= 1;
    }
  }

  // dump columns straight to workspace (col-major per matrix, stride 100)
  if (act) {
    float* Gb = Gout + (size_t)b*SPD_*SPD_;
    #pragma unroll
    for (int i = 0; i < 12; ++i) {
      Gb[j*SPD_ + rb + 2*i]   = A2[i].x;
      Gb[j*SPD_ + rb + 2*i+1] = A2[i].y;
      Gb[(50 + j)*SPD_ + rb + 2*i]   = B2[i].x;
      Gb[(50 + j)*SPD_ + rb + 2*i+1] = B2[i].y;
    }
    Gb[j*SPD_ + rb + 24]        = As;
    Gb[(50 + j)*SPD_ + rb + 24] = Bs;
  }
}

// ---------------------------------------------------------------------------
// K5b (merged with FC): per-column fp64 norms -> wc = log(clip(lam,1e-6))/lam^2,
// L = sum_c wc[c] g_c g_c^T -> scaled upper-tri flat -> out[64 + b*5050 + idx],
// and logits = flat @ w_fc^T + b_fc accumulated in the same pass.
// ---------------------------------------------------------------------------
__global__ __launch_bounds__(256) void k_lout(const float* __restrict__ Gin,
                                              const float* __restrict__ wfc,
                                              const float* __restrict__ bfc,
                                              float* __restrict__ out) {
  __shared__ __align__(16) float G[SPD_*SPD_];
  __shared__ float wcs[SPD_];
  __shared__ float red[8];
  const int tid = threadIdx.x;
  const int b   = blockIdx.x;
  for (int idx = tid; idx < SPD_*SPD_; idx += 256)
    G[idx] = Gin[(size_t)b*SPD_*SPD_ + idx];
  __syncthreads();
  if (tid < SPD_) {
    const float* col = &G[tid*SPD_];
    double s = 0.0;
    for (int i = 0; i < SPD_; ++i) { double v = (double)col[i]; s += v*v; }
    double lam = sqrt(s);
    double lc  = (lam < 1e-6) ? 1e-6 : lam;
    wcs[tid] = (float)(log(lc) / ((s > 1e-300) ? s : 1e-300));
  }
  __syncthreads();

  float a0 = 0.f, a1 = 0.f, a2 = 0.f, a3 = 0.f;
  for (int tile = tid; tile < 625; tile += 256) {
    const int ti = (tile / 25) * 4;
    const int tj = (tile % 25) * 4;
    float acc[4][4];
    #pragma unroll
    for (int r = 0; r < 4; ++r)
      #pragma unroll
      for (int s = 0; s < 4; ++s) acc[r][s] = 0.f;
    for (int c = 0; c < SPD_; ++c) {
      const float* col = &G[c*SPD_];
      float4 ga = *(const float4*)&col[ti];
      float4 gb = *(const float4*)&col[tj];
      float wcv = wcs[c];
      float wa[4] = { wcv*ga.x, wcv*ga.y, wcv*ga.z, wcv*ga.w };
      float bv[4] = { gb.x, gb.y, gb.z, gb.w };
      #pragma unroll
      for (int r = 0; r < 4; ++r)
        #pragma unroll
        for (int s = 0; s < 4; ++s) acc[r][s] += wa[r]*bv[s];
    }
    const float RT2 = 1.41421356237309505f;
    #pragma unroll
    for (int r = 0; r < 4; ++r) {
      #pragma unroll
      for (int s = 0; s < 4; ++s) {
        int i = ti + r, jx = tj + s;
        if (i <= jx) {
          int idx = i*SPD_ - (i*(i+1))/2 + jx;
          float val = acc[r][s] * (i == jx ? 1.f : RT2);
          out[64 + b*5050 + idx] = val;
          a0 += val * wfc[idx];
          a1 += val * wfc[5050 + idx];
          a2 += val * wfc[10100 + idx];
          a3 += val * wfc[15150 + idx];
        }
      }
    }
  }
  a0 = block_sum(a0, red);
  a1 = block_sum(a1, red);
  a2 = block_sum(a2, red);
  a3 = block_sum(a3, red);
  if (tid == 0) {
    out[b*4 + 0] = a0 + bfc[0];
    out[b*4 + 1] = a1 + bfc[1];
    out[b*4 + 2] = a2 + bfc[2];
    out[b*4 + 3] = a3 + bfc[3];
  }
}

extern "C" void kernel_launch(void* const* d_in, const int* in_sizes, int n_in,
                              void* d_out, int out_size, void* d_ws, size_t ws_size,
                              hipStream_t stream) {
  (void)in_sizes; (void)n_in; (void)out_size; (void)ws_size;
  const float* x = (const float*)d_in[0];
  const float* bw[3][9];
  for (int i = 0; i < 3; ++i)
    for (int jx = 0; jx < 9; ++jx)
      bw[i][jx] = (const float*)d_in[1 + i*9 + jx];
  const float* w_sconv = (const float*)d_in[28];
  const float* w_aff   = (const float*)d_in[29];
  const float* w_fc    = (const float*)d_in[30];
  const float* b_fc    = (const float*)d_in[31];

  char* ws = (char*)d_ws;
  float*  hcat = (float*)(ws + OFF_HCAT);
  float*  xc   = (float*)(ws + OFF_XC);
  float*  cov  = (float*)(ws + OFF_COV);
  float*  P    = (float*)(ws + OFF_P);
  float*  G    = (float*)(ws + OFF_G);    // reuses xc region (dead after k_cov)
  float*  out  = (float*)d_out;

  PrepPtrs pp; FrontPtrs fp;
  for (int i = 0; i < 3; ++i) {
    pp.w1[i] = bw[i][0]; pp.w2[i] = bw[i][1]; pp.w3[i] = bw[i][2]; pp.w4[i] = bw[i][3];
    fp.g1[i] = bw[i][4]; fp.b1[i] = bw[i][5]; fp.w5[i] = bw[i][6];
    fp.g2[i] = bw[i][7]; fp.b2[i] = bw[i][8];
  }
  fp.K[0] = 15; fp.K[1] = 75; fp.K[2] = 55;

  hipLaunchKernelGGL(k_front, dim3(3*B_*FCH_),    dim3(256), 0, stream, x, pp, fp, hcat);
  hipLaunchKernelGGL(k_sconv, dim3(B_*10),        dim3(256), 0, stream, hcat, w_sconv, xc);
  hipLaunchKernelGGL(k_cov,   dim3(B_*5),         dim3(256), 0, stream, xc, cov);
  hipLaunchKernelGGL(k_aff,   dim3(B_*5),         dim3(256), 0, stream, cov, w_aff, P);
  hipLaunchKernelGGL(k_eig,   dim3(B_),           dim3(256), 0, stream, P, G);
  hipLaunchKernelGGL(k_lout,  dim3(B_),           dim3(256), 0, stream, G, w_fc, b_fc, out);
}